// Round 7
// baseline (330.074 us; speedup 1.0000x reference)
//
#include <hip/hip_runtime.h>
#include <hip/hip_bf16.h>

typedef __attribute__((ext_vector_type(8))) short short8;
typedef __attribute__((ext_vector_type(4))) float floatx4;

constexpr int SQ  = 2048;
constexpr int NBH = 32;     // b*h
constexpr int D   = 128;
constexpr int RS  = 4096;   // fp32 row stride (b*h*d)
constexpr int BM  = 128;    // q rows per block (4 waves x 32 rows)
constexpr int BN  = 64;     // kv rows per tile
constexpr int VP  = 72;     // Ps pitch in shorts

// softmax_scale * log2(e): fold into Q so softmax uses exp2 directly
#define SCALE_LOG2E 0.1275310225629712f

__device__ __forceinline__ unsigned int pack2bf(float a, float b) {
  __hip_bfloat162 h = __float22bfloat162_rn(make_float2(a, b));
  union { __hip_bfloat162 h; unsigned int u; } cv; cv.h = h;
  return cv.u;
}

__device__ __forceinline__ void gl_lds16(const unsigned short* g, unsigned short* l) {
  __builtin_amdgcn_global_load_lds(
      (const __attribute__((address_space(1))) unsigned int*)g,
      (__attribute__((address_space(3))) unsigned int*)l, 16, 0, 0);
}

// ============ pre-pass: K -> bf16 [bh][key][d]; V -> bf16 V^T [bh][d][key] ============
__global__ __launch_bounds__(256)
void prep_kernel(const float* __restrict__ K, const float* __restrict__ V,
                 unsigned short* __restrict__ Kg, unsigned short* __restrict__ Vtg) {
  __shared__ __align__(16) unsigned short Vl[D * 64];   // 16 KB
  const int bh  = blockIdx.x;
  const int j0  = blockIdx.y * BN;
  const int tid = threadIdx.x;

  const float* Kb = K + (size_t)j0 * RS + bh * D;
  unsigned short* Ko = Kg + ((size_t)bh * SQ + j0) * D;
  #pragma unroll
  for (int it = 0; it < 8; ++it) {
    int chunk = tid + it * 256;
    int r = chunk >> 5, c = chunk & 31;
    float4 kv = *(const float4*)(Kb + r * RS + c * 4);
    uint2 u; u.x = pack2bf(kv.x, kv.y); u.y = pack2bf(kv.z, kv.w);
    *(uint2*)&Ko[r * 128 + c * 4] = u;
  }

  const int sc = tid & 31;   // d-group (float4)
  const int sg = tid >> 5;   // key-chunk (8 keys)
  const float* Vb = V + (size_t)j0 * RS + bh * D;
  float4 vr[8];
  #pragma unroll
  for (int j = 0; j < 8; ++j)
    vr[j] = *(const float4*)(Vb + (sg * 8 + j) * RS + sc * 4);
  #pragma unroll
  for (int i = 0; i < 4; ++i) {
    int d = sc * 4 + i;
    int swz = ((d >> 2) ^ d) & 7;
    union { short8 s; unsigned int u[4]; } w;
    w.u[0] = pack2bf(((const float*)&vr[0])[i], ((const float*)&vr[1])[i]);
    w.u[1] = pack2bf(((const float*)&vr[2])[i], ((const float*)&vr[3])[i]);
    w.u[2] = pack2bf(((const float*)&vr[4])[i], ((const float*)&vr[5])[i]);
    w.u[3] = pack2bf(((const float*)&vr[6])[i], ((const float*)&vr[7])[i]);
    *(short8*)&Vl[d * 64 + ((sg ^ swz) * 8)] = w.s;
  }
  __syncthreads();

  unsigned short* Vo = Vtg + (size_t)bh * D * SQ;
  #pragma unroll
  for (int p = 0; p < 4; ++p) {
    int c  = p * 256 + tid;
    int d  = c >> 3, kc = c & 7;
    int swz = ((d >> 2) ^ d) & 7;
    short8 v = *(const short8*)&Vl[d * 64 + ((kc ^ swz) * 8)];
    *(short8*)&Vo[(size_t)d * SQ + j0 + kc * 8] = v;
  }
}

// ============ main flash kernel: 4 waves x 32 q-rows, b-frags shared 2x ============
__global__ __launch_bounds__(256, 3)
void fa_fwd_kernel(const float* __restrict__ Q,
                   const unsigned short* __restrict__ Kg,
                   const unsigned short* __restrict__ Vtg,
                   float* __restrict__ Out) {
  __shared__ __align__(16) unsigned short Ks[BN * 128];   // 16384 B
  __shared__ __align__(16) unsigned short Vt[D * 64];     // 16384 B
  __shared__ __align__(16) unsigned short Ps[BM * VP];    // 18432 B
  // total 51200 B -> 3 blocks/CU

  const int tid  = threadIdx.x;
  const int bh   = blockIdx.x;
  const int qt   = (gridDim.y - 1) - blockIdx.y;  // heavy blocks first
  const int q0   = qt * BM;
  const int w    = tid >> 6;     // wave 0..3, owns rows rbase..rbase+31
  const int lane = tid & 63;
  const int quad = lane >> 4;
  const int col  = lane & 15;
  const int rbase = w * 32;

  const unsigned short* Kgb  = Kg  + (size_t)bh * SQ * D;
  const unsigned short* Vtgb = Vtg + (size_t)bh * D * SQ;

  // ---- Q fragments for both 16-row halves ----
  short8 qfrag[2][4];
  #pragma unroll
  for (int h = 0; h < 2; ++h) {
    const int qrow = q0 + rbase + h * 16 + col;
    const float* Qr = Q + (size_t)qrow * RS + bh * D;
    #pragma unroll
    for (int ks = 0; ks < 4; ++ks) {
      float4 a0 = *(const float4*)(Qr + ks * 32 + quad * 8);
      float4 a1 = *(const float4*)(Qr + ks * 32 + quad * 8 + 4);
      union { short8 s; unsigned int u[4]; } qf;
      qf.u[0] = pack2bf(a0.x * SCALE_LOG2E, a0.y * SCALE_LOG2E);
      qf.u[1] = pack2bf(a0.z * SCALE_LOG2E, a0.w * SCALE_LOG2E);
      qf.u[2] = pack2bf(a1.x * SCALE_LOG2E, a1.y * SCALE_LOG2E);
      qf.u[3] = pack2bf(a1.z * SCALE_LOG2E, a1.w * SCALE_LOG2E);
      qfrag[h][ks] = qf.s;
    }
  }

  floatx4 Oacc[2][8];
  #pragma unroll
  for (int h = 0; h < 2; ++h)
    #pragma unroll
    for (int dt = 0; dt < 8; ++dt)
      #pragma unroll
      for (int e = 0; e < 4; ++e) Oacc[h][dt][e] = 0.f;
  float lsum[2][4] = {{0.f,0.f,0.f,0.f},{0.f,0.f,0.f,0.f}};

  // 32 aligned rows never straddle a 64-row kv-tile: both halves share jt_max/diag
  const int wave_jt_max = (q0 + rbase + 31) >> 6;
  const int jt_max      = 2 * qt + 1;

  for (int jt = 0; jt <= jt_max; ++jt) {
    const int j0 = jt * BN;
    __syncthreads();   // prior tile's LDS reads complete

    // ---- staging: 32 x 1KB segments, 8 global_load_lds_dwordx4 per wave ----
    #pragma unroll
    for (int t = 0; t < 8; ++t) {
      const int n = w * 8 + t;          // wave-uniform
      if (n < 16) {                      // Ks segment n: keys 4n..4n+3
        const int kl = n * 4 + (lane >> 4);
        const int pc = lane & 15;
        const int lc = pc ^ (kl & 7);
        gl_lds16(Kgb + (size_t)(j0 + kl) * 128 + lc * 8, &Ks[n * 512]);
      } else {                           // Vt segment s: d rows 8s..8s+7
        const int s  = n - 16;
        const int d  = s * 8 + (lane >> 3);
        const int pc = lane & 7;
        const int lc = pc ^ (d & 7);
        gl_lds16(Vtgb + (size_t)d * SQ + j0 + lc * 8, &Vt[s * 512]);
      }
    }
    __syncthreads();   // implicit vmcnt(0): staged data visible

    if (jt > wave_jt_max) continue;   // wave-uniform

    // ---- S = Q K^T : each b-frag feeds both halves ----
    floatx4 S[2][4];
    #pragma unroll
    for (int h = 0; h < 2; ++h)
      #pragma unroll
      for (int nt = 0; nt < 4; ++nt)
        #pragma unroll
        for (int e = 0; e < 4; ++e) S[h][nt][e] = 0.f;
    #pragma unroll
    for (int ks = 0; ks < 4; ++ks) {
      short8 a0 = qfrag[0][ks];
      short8 a1 = qfrag[1][ks];
      #pragma unroll
      for (int nt = 0; nt < 4; ++nt) {
        const int r  = nt * 16 + col;
        const int pc = (ks * 4 + quad) ^ (col & 7);
        short8 b = *(const short8*)&Ks[r * 128 + pc * 8];
        S[0][nt] = __builtin_amdgcn_mfma_f32_16x16x32_bf16(a0, b, S[0][nt], 0, 0, 0);
        S[1][nt] = __builtin_amdgcn_mfma_f32_16x16x32_bf16(a1, b, S[1][nt], 0, 0, 0);
      }
    }

    // ---- mask + exp2 (fixed-max softmax) + lsum + Ps write ----
    const bool diag = (jt == wave_jt_max);
    #pragma unroll
    for (int h = 0; h < 2; ++h) {
      const int row0 = q0 + rbase + h * 16 + quad * 4;
      const int prow = rbase + h * 16 + quad * 4;
      #pragma unroll
      for (int nt = 0; nt < 4; ++nt) {
        const int key = j0 + nt * 16 + col;
        float pv[4];
        #pragma unroll
        for (int r = 0; r < 4; ++r) {
          float s = S[h][nt][r];
          if (diag && key > row0 + r) s = -INFINITY;
          pv[r] = __builtin_amdgcn_exp2f(s);
          lsum[h][r] += pv[r];
        }
        union { unsigned int u; unsigned short s2[2]; } c01, c23;
        c01.u = pack2bf(pv[0], pv[1]);
        c23.u = pack2bf(pv[2], pv[3]);
        const int cc = nt * 16 + col;
        Ps[(prow + 0) * VP + cc] = c01.s2[0];
        Ps[(prow + 1) * VP + cc] = c01.s2[1];
        Ps[(prow + 2) * VP + cc] = c23.s2[0];
        Ps[(prow + 3) * VP + cc] = c23.s2[1];
      }
    }

    // ---- O += P V : each b-frag feeds both halves ----
    #pragma unroll
    for (int ks = 0; ks < 2; ++ks) {
      short8 aA = *(const short8*)&Ps[(rbase + col) * VP + ks * 32 + quad * 8];
      short8 aB = *(const short8*)&Ps[(rbase + 16 + col) * VP + ks * 32 + quad * 8];
      #pragma unroll
      for (int dt = 0; dt < 8; ++dt) {
        const int d  = dt * 16 + col;
        const int pc = (ks * 4 + quad) ^ (col & 7);
        short8 b = *(const short8*)&Vt[d * 64 + pc * 8];
        Oacc[0][dt] = __builtin_amdgcn_mfma_f32_16x16x32_bf16(aA, b, Oacc[0][dt], 0, 0, 0);
        Oacc[1][dt] = __builtin_amdgcn_mfma_f32_16x16x32_bf16(aB, b, Oacc[1][dt], 0, 0, 0);
      }
    }
  }

  // ---- epilogue: l reduction + normalize + store ----
  #pragma unroll
  for (int h = 0; h < 2; ++h) {
    #pragma unroll
    for (int r = 0; r < 4; ++r) {
      float s = lsum[h][r];
      #pragma unroll
      for (int off = 1; off < 16; off <<= 1)
        s += __shfl_xor(s, off, 64);
      float inv = 1.f / s;
      int row_g = q0 + rbase + h * 16 + quad * 4 + r;
      float* Ob = Out + (size_t)row_g * RS + bh * D;
      #pragma unroll
      for (int dt = 0; dt < 8; ++dt)
        Ob[dt * 16 + col] = Oacc[h][dt][r] * inv;
    }
  }
}

// ============ fallback (round-6) if ws_size < 32 MB ============
__global__ __launch_bounds__(512, 2)
void fa_fwd_kernel_fb(const float* __restrict__ Q,
                      const float* __restrict__ K,
                      const float* __restrict__ V,
                      float* __restrict__ Out) {
  __shared__ __align__(16) unsigned short Ks[BN * 136];
  __shared__ __align__(16) unsigned short Vt[D * 64];
  __shared__ __align__(16) unsigned short Ps[8 * 16 * VP];

  const int tid  = threadIdx.x;
  const int bh   = blockIdx.x;
  const int qt   = gridDim.y - 1 - blockIdx.y;
  const int q0   = qt * BM;
  const int w    = tid >> 6;
  const int lane = tid & 63;
  const int quad = lane >> 4;
  const int col  = lane & 15;

  const int qrow = q0 + w * 16 + col;
  const float* Qr = Q + (size_t)qrow * RS + bh * D;
  short8 qfrag[4];
  #pragma unroll
  for (int ks = 0; ks < 4; ++ks) {
    float4 a0 = *(const float4*)(Qr + ks * 32 + quad * 8);
    float4 a1 = *(const float4*)(Qr + ks * 32 + quad * 8 + 4);
    union { short8 s; unsigned int u[4]; } qf;
    qf.u[0] = pack2bf(a0.x * SCALE_LOG2E, a0.y * SCALE_LOG2E);
    qf.u[1] = pack2bf(a0.z * SCALE_LOG2E, a0.w * SCALE_LOG2E);
    qf.u[2] = pack2bf(a1.x * SCALE_LOG2E, a1.y * SCALE_LOG2E);
    qf.u[3] = pack2bf(a1.z * SCALE_LOG2E, a1.w * SCALE_LOG2E);
    qfrag[ks] = qf.s;
  }

  floatx4 Oacc[8];
  #pragma unroll
  for (int dt = 0; dt < 8; ++dt) {
    #pragma unroll
    for (int e = 0; e < 4; ++e) Oacc[dt][e] = 0.f;
  }
  float lsum[4] = {0.f, 0.f, 0.f, 0.f};

  const int row_g0      = q0 + w * 16 + quad * 4;
  const int jt_maxb     = (q0 + BM - 1) >> 6;
  const int wave_jt_max = (q0 + w * 16 + 15) >> 6;

  for (int jt = 0; jt <= jt_maxb; ++jt) {
    const int j0 = jt * BN;
    __syncthreads();
    if (tid < 256) {
      const int sc = tid & 31;
      const int sg = tid >> 5;
      const float* Vb = V + (size_t)j0 * RS + bh * D;
      float4 vr[8];
      #pragma unroll
      for (int j = 0; j < 8; ++j)
        vr[j] = *(const float4*)(Vb + (sg * 8 + j) * RS + sc * 4);
      #pragma unroll
      for (int i = 0; i < 4; ++i) {
        int d = sc * 4 + i;
        int swz = ((d >> 2) ^ d) & 7;
        union { short8 s; unsigned int u[4]; } wv;
        wv.u[0] = pack2bf(((const float*)&vr[0])[i], ((const float*)&vr[1])[i]);
        wv.u[1] = pack2bf(((const float*)&vr[2])[i], ((const float*)&vr[3])[i]);
        wv.u[2] = pack2bf(((const float*)&vr[4])[i], ((const float*)&vr[5])[i]);
        wv.u[3] = pack2bf(((const float*)&vr[6])[i], ((const float*)&vr[7])[i]);
        *(short8*)&Vt[d * 64 + ((sg ^ swz) * 8)] = wv.s;
      }
    } else {
      const int kt = tid - 256;
      const float* Kb = K + (size_t)j0 * RS + bh * D;
      #pragma unroll
      for (int it = 0; it < 8; ++it) {
        int chunk = kt + it * 256;
        int r = chunk >> 5, c = chunk & 31;
        float4 kv = *(const float4*)(Kb + r * RS + c * 4);
        uint2 u; u.x = pack2bf(kv.x, kv.y); u.y = pack2bf(kv.z, kv.w);
        *(uint2*)&Ks[r * 136 + c * 4] = u;
      }
    }
    __syncthreads();

    if (jt > wave_jt_max) continue;

    floatx4 S[4];
    #pragma unroll
    for (int nt = 0; nt < 4; ++nt) {
      #pragma unroll
      for (int e = 0; e < 4; ++e) S[nt][e] = 0.f;
    }
    #pragma unroll
    for (int ks = 0; ks < 4; ++ks) {
      short8 a = qfrag[ks];
      #pragma unroll
      for (int nt = 0; nt < 4; ++nt) {
        short8 b = *(const short8*)&Ks[(nt * 16 + col) * 136 + ks * 32 + quad * 8];
        S[nt] = __builtin_amdgcn_mfma_f32_16x16x32_bf16(a, b, S[nt], 0, 0, 0);
      }
    }

    const bool diag = (jt == wave_jt_max);
    float p[4][4];
    #pragma unroll
    for (int nt = 0; nt < 4; ++nt) {
      int key = j0 + nt * 16 + col;
      #pragma unroll
      for (int r = 0; r < 4; ++r) {
        float s = S[nt][r];
        if (diag && key > row_g0 + r) s = -INFINITY;
        float pe = __builtin_amdgcn_exp2f(s);
        p[nt][r] = pe;
        lsum[r] += pe;
      }
    }

    #pragma unroll
    for (int nt = 0; nt < 4; ++nt) {
      #pragma unroll
      for (int r = 0; r < 4; ++r) {
        union { float f; unsigned int u; } cv;
        cv.f = p[nt][r];
        unsigned int u = cv.u;
        u += 0x7fffu + ((u >> 16) & 1u);
        Ps[(w * 16 + quad * 4 + r) * VP + nt * 16 + col] = (unsigned short)(u >> 16);
      }
    }

    #pragma unroll
    for (int ks = 0; ks < 2; ++ks) {
      short8 a = *(const short8*)&Ps[(w * 16 + col) * VP + ks * 32 + quad * 8];
      #pragma unroll
      for (int dt = 0; dt < 8; ++dt) {
        int d = dt * 16 + col;
        int swz = ((d >> 2) ^ d) & 7;
        short8 b = *(const short8*)&Vt[d * 64 + (((ks * 4 + quad) ^ swz) * 8)];
        Oacc[dt] = __builtin_amdgcn_mfma_f32_16x16x32_bf16(a, b, Oacc[dt], 0, 0, 0);
      }
    }
  }

  #pragma unroll
  for (int r = 0; r < 4; ++r) {
    float s = lsum[r];
    #pragma unroll
    for (int off = 1; off < 16; off <<= 1)
      s += __shfl_xor(s, off, 64);
    float inv = 1.f / s;
    int row_g = q0 + w * 16 + quad * 4 + r;
    float* Ob = Out + (size_t)row_g * RS + bh * D;
    #pragma unroll
    for (int dt = 0; dt < 8; ++dt)
      Ob[dt * 16 + col] = Oacc[dt][r] * inv;
  }
}

extern "C" void kernel_launch(void* const* d_in, const int* in_sizes, int n_in,
                              void* d_out, int out_size, void* d_ws, size_t ws_size,
                              hipStream_t stream) {
  const float* Q = (const float*)d_in[0];
  const float* K = (const float*)d_in[1];
  const float* V = (const float*)d_in[2];
  float* Out = (float*)d_out;
  const size_t need = (size_t)2 * NBH * SQ * D * sizeof(unsigned short); // 32 MB
  if (ws_size >= need) {
    unsigned short* Kg  = (unsigned short*)d_ws;
    unsigned short* Vtg = Kg + (size_t)NBH * SQ * D;
    prep_kernel<<<dim3(NBH, SQ / BN), dim3(256), 0, stream>>>(K, V, Kg, Vtg);
    fa_fwd_kernel<<<dim3(NBH, SQ / BM), dim3(256), 0, stream>>>(Q, Kg, Vtg, Out);
  } else {
    fa_fwd_kernel_fb<<<dim3(NBH, SQ / BM), dim3(512), 0, stream>>>(Q, K, V, Out);
  }
}

// Round 8
// 211.753 us; speedup vs baseline: 1.5588x; 1.5588x over previous
//
#include <hip/hip_runtime.h>
#include <hip/hip_bf16.h>

typedef __attribute__((ext_vector_type(8))) short short8;
typedef __attribute__((ext_vector_type(4))) float floatx4;

constexpr int SQ  = 2048;
constexpr int NBH = 32;     // b*h
constexpr int D   = 128;
constexpr int RS  = 4096;   // fp32 row stride (b*h*d)
constexpr int BM  = 128;    // q rows per block (4 waves x 32 rows)
constexpr int BN  = 64;     // kv rows per tile
constexpr int VP  = 72;     // Ps pitch in shorts

// softmax_scale * log2(e): fold into Q so softmax uses exp2 directly
#define SCALE_LOG2E 0.1275310225629712f

__device__ __forceinline__ unsigned int pack2bf(float a, float b) {
  __hip_bfloat162 h = __float22bfloat162_rn(make_float2(a, b));
  union { __hip_bfloat162 h; unsigned int u; } cv; cv.h = h;
  return cv.u;
}

__device__ __forceinline__ void gl_lds16(const unsigned short* g, unsigned short* l) {
  __builtin_amdgcn_global_load_lds(
      (const __attribute__((address_space(1))) unsigned int*)g,
      (__attribute__((address_space(3))) unsigned int*)l, 16, 0, 0);
}

// ============ pre-pass: K -> bf16 [bh][key][d]; V -> bf16 V^T [bh][d][key] ============
__global__ __launch_bounds__(256)
void prep_kernel(const float* __restrict__ K, const float* __restrict__ V,
                 unsigned short* __restrict__ Kg, unsigned short* __restrict__ Vtg) {
  __shared__ __align__(16) unsigned short Vl[D * 64];   // 16 KB
  const int bh  = blockIdx.x;
  const int j0  = blockIdx.y * BN;
  const int tid = threadIdx.x;

  const float* Kb = K + (size_t)j0 * RS + bh * D;
  unsigned short* Ko = Kg + ((size_t)bh * SQ + j0) * D;
  #pragma unroll
  for (int it = 0; it < 8; ++it) {
    int chunk = tid + it * 256;
    int r = chunk >> 5, c = chunk & 31;
    float4 kv = *(const float4*)(Kb + r * RS + c * 4);
    uint2 u; u.x = pack2bf(kv.x, kv.y); u.y = pack2bf(kv.z, kv.w);
    *(uint2*)&Ko[r * 128 + c * 4] = u;
  }

  const int sc = tid & 31;   // d-group (float4)
  const int sg = tid >> 5;   // key-chunk (8 keys)
  const float* Vb = V + (size_t)j0 * RS + bh * D;
  float4 vr[8];
  #pragma unroll
  for (int j = 0; j < 8; ++j)
    vr[j] = *(const float4*)(Vb + (sg * 8 + j) * RS + sc * 4);
  #pragma unroll
  for (int i = 0; i < 4; ++i) {
    int d = sc * 4 + i;
    int swz = ((d >> 2) ^ d) & 7;
    union { short8 s; unsigned int u[4]; } w;
    w.u[0] = pack2bf(((const float*)&vr[0])[i], ((const float*)&vr[1])[i]);
    w.u[1] = pack2bf(((const float*)&vr[2])[i], ((const float*)&vr[3])[i]);
    w.u[2] = pack2bf(((const float*)&vr[4])[i], ((const float*)&vr[5])[i]);
    w.u[3] = pack2bf(((const float*)&vr[6])[i], ((const float*)&vr[7])[i]);
    *(short8*)&Vl[d * 64 + ((sg ^ swz) * 8)] = w.s;
  }
  __syncthreads();

  unsigned short* Vo = Vtg + (size_t)bh * D * SQ;
  #pragma unroll
  for (int p = 0; p < 4; ++p) {
    int c  = p * 256 + tid;
    int d  = c >> 3, kc = c & 7;
    int swz = ((d >> 2) ^ d) & 7;
    short8 v = *(const short8*)&Vl[d * 64 + ((kc ^ swz) * 8)];
    *(short8*)&Vo[(size_t)d * SQ + j0 + kc * 8] = v;
  }
}

// ============ main flash kernel: 4 waves x 32 q-rows, b-frags shared 2x ============
// NO waves-per-EU cap: round-7's (256,3) capped arch VGPRs at 84 and spilled
// ~50 regs to scratch (+23 MB WRITE_SIZE, 2.4x slower). S is streamed per
// nt-tile (8 live regs instead of 32) to keep peak pressure modest.
__global__ __launch_bounds__(256)
void fa_fwd_kernel(const float* __restrict__ Q,
                   const unsigned short* __restrict__ Kg,
                   const unsigned short* __restrict__ Vtg,
                   float* __restrict__ Out) {
  __shared__ __align__(16) unsigned short Ks[BN * 128];   // 16384 B
  __shared__ __align__(16) unsigned short Vt[D * 64];     // 16384 B
  __shared__ __align__(16) unsigned short Ps[BM * VP];    // 18432 B

  const int tid  = threadIdx.x;
  const int bh   = blockIdx.x;
  const int qt   = (gridDim.y - 1) - blockIdx.y;  // heavy blocks first
  const int q0   = qt * BM;
  const int w    = tid >> 6;     // wave 0..3, owns rows rbase..rbase+31
  const int lane = tid & 63;
  const int quad = lane >> 4;
  const int col  = lane & 15;
  const int rbase = w * 32;

  const unsigned short* Kgb  = Kg  + (size_t)bh * SQ * D;
  const unsigned short* Vtgb = Vtg + (size_t)bh * D * SQ;

  // ---- Q fragments for both 16-row halves ----
  short8 qfrag[2][4];
  #pragma unroll
  for (int h = 0; h < 2; ++h) {
    const int qrow = q0 + rbase + h * 16 + col;
    const float* Qr = Q + (size_t)qrow * RS + bh * D;
    #pragma unroll
    for (int ks = 0; ks < 4; ++ks) {
      float4 a0 = *(const float4*)(Qr + ks * 32 + quad * 8);
      float4 a1 = *(const float4*)(Qr + ks * 32 + quad * 8 + 4);
      union { short8 s; unsigned int u[4]; } qf;
      qf.u[0] = pack2bf(a0.x * SCALE_LOG2E, a0.y * SCALE_LOG2E);
      qf.u[1] = pack2bf(a0.z * SCALE_LOG2E, a0.w * SCALE_LOG2E);
      qf.u[2] = pack2bf(a1.x * SCALE_LOG2E, a1.y * SCALE_LOG2E);
      qf.u[3] = pack2bf(a1.z * SCALE_LOG2E, a1.w * SCALE_LOG2E);
      qfrag[h][ks] = qf.s;
    }
  }

  floatx4 Oacc[2][8];
  #pragma unroll
  for (int h = 0; h < 2; ++h)
    #pragma unroll
    for (int dt = 0; dt < 8; ++dt)
      #pragma unroll
      for (int e = 0; e < 4; ++e) Oacc[h][dt][e] = 0.f;
  float lsum[2][4] = {{0.f,0.f,0.f,0.f},{0.f,0.f,0.f,0.f}};

  // 32 aligned rows never straddle a 64-row kv-tile: halves share jt_max/diag
  const int wave_jt_max = (q0 + rbase + 31) >> 6;
  const int jt_max      = 2 * qt + 1;

  for (int jt = 0; jt <= jt_max; ++jt) {
    const int j0 = jt * BN;
    __syncthreads();   // prior tile's LDS reads complete

    // ---- staging: 32 x 1KB segments, 8 global_load_lds_dwordx4 per wave ----
    #pragma unroll
    for (int t = 0; t < 8; ++t) {
      const int n = w * 8 + t;          // wave-uniform
      if (n < 16) {                      // Ks segment n: keys 4n..4n+3
        const int kl = n * 4 + (lane >> 4);
        const int pc = lane & 15;
        const int lc = pc ^ (kl & 7);
        gl_lds16(Kgb + (size_t)(j0 + kl) * 128 + lc * 8, &Ks[n * 512]);
      } else {                           // Vt segment s: d rows 8s..8s+7
        const int s  = n - 16;
        const int d  = s * 8 + (lane >> 3);
        const int pc = lane & 7;
        const int lc = pc ^ (d & 7);
        gl_lds16(Vtgb + (size_t)d * SQ + j0 + lc * 8, &Vt[s * 512]);
      }
    }
    __syncthreads();   // implicit vmcnt(0): staged data visible

    if (jt > wave_jt_max) continue;   // wave-uniform

    const bool diag = (jt == wave_jt_max);

    // ---- streamed S per nt: QK -> mask -> exp2 -> lsum -> Ps ----
    #pragma unroll
    for (int nt = 0; nt < 4; ++nt) {
      floatx4 S0, S1;
      #pragma unroll
      for (int e = 0; e < 4; ++e) { S0[e] = 0.f; S1[e] = 0.f; }
      #pragma unroll
      for (int ks = 0; ks < 4; ++ks) {
        const int r  = nt * 16 + col;
        const int pc = (ks * 4 + quad) ^ (col & 7);
        short8 b = *(const short8*)&Ks[r * 128 + pc * 8];
        S0 = __builtin_amdgcn_mfma_f32_16x16x32_bf16(qfrag[0][ks], b, S0, 0, 0, 0);
        S1 = __builtin_amdgcn_mfma_f32_16x16x32_bf16(qfrag[1][ks], b, S1, 0, 0, 0);
      }
      const int key = j0 + nt * 16 + col;
      const int cc  = nt * 16 + col;
      #pragma unroll
      for (int h = 0; h < 2; ++h) {
        const int row0 = q0 + rbase + h * 16 + quad * 4;
        const int prow = rbase + h * 16 + quad * 4;
        float pv[4];
        #pragma unroll
        for (int r = 0; r < 4; ++r) {
          float s = h ? S1[r] : S0[r];
          if (diag && key > row0 + r) s = -INFINITY;
          pv[r] = __builtin_amdgcn_exp2f(s);
          lsum[h][r] += pv[r];
        }
        union { unsigned int u; unsigned short s2[2]; } c01, c23;
        c01.u = pack2bf(pv[0], pv[1]);
        c23.u = pack2bf(pv[2], pv[3]);
        Ps[(prow + 0) * VP + cc] = c01.s2[0];
        Ps[(prow + 1) * VP + cc] = c01.s2[1];
        Ps[(prow + 2) * VP + cc] = c23.s2[0];
        Ps[(prow + 3) * VP + cc] = c23.s2[1];
      }
    }

    // ---- O += P V : each b-frag feeds both halves ----
    #pragma unroll
    for (int ks = 0; ks < 2; ++ks) {
      short8 aA = *(const short8*)&Ps[(rbase + col) * VP + ks * 32 + quad * 8];
      short8 aB = *(const short8*)&Ps[(rbase + 16 + col) * VP + ks * 32 + quad * 8];
      #pragma unroll
      for (int dt = 0; dt < 8; ++dt) {
        const int d  = dt * 16 + col;
        const int pc = (ks * 4 + quad) ^ (col & 7);
        short8 b = *(const short8*)&Vt[d * 64 + pc * 8];
        Oacc[0][dt] = __builtin_amdgcn_mfma_f32_16x16x32_bf16(aA, b, Oacc[0][dt], 0, 0, 0);
        Oacc[1][dt] = __builtin_amdgcn_mfma_f32_16x16x32_bf16(aB, b, Oacc[1][dt], 0, 0, 0);
      }
    }
  }

  // ---- epilogue: l reduction + normalize + store ----
  #pragma unroll
  for (int h = 0; h < 2; ++h) {
    #pragma unroll
    for (int r = 0; r < 4; ++r) {
      float s = lsum[h][r];
      #pragma unroll
      for (int off = 1; off < 16; off <<= 1)
        s += __shfl_xor(s, off, 64);
      float inv = 1.f / s;
      int row_g = q0 + rbase + h * 16 + quad * 4 + r;
      float* Ob = Out + (size_t)row_g * RS + bh * D;
      #pragma unroll
      for (int dt = 0; dt < 8; ++dt)
        Ob[dt * 16 + col] = Oacc[h][dt][r] * inv;
    }
  }
}

// ============ fallback (round-6) if ws_size < 32 MB ============
__global__ __launch_bounds__(512, 2)
void fa_fwd_kernel_fb(const float* __restrict__ Q,
                      const float* __restrict__ K,
                      const float* __restrict__ V,
                      float* __restrict__ Out) {
  __shared__ __align__(16) unsigned short Ks[BN * 136];
  __shared__ __align__(16) unsigned short Vt[D * 64];
  __shared__ __align__(16) unsigned short Ps[8 * 16 * VP];

  const int tid  = threadIdx.x;
  const int bh   = blockIdx.x;
  const int qt   = gridDim.y - 1 - blockIdx.y;
  const int q0   = qt * BM;
  const int w    = tid >> 6;
  const int lane = tid & 63;
  const int quad = lane >> 4;
  const int col  = lane & 15;

  const int qrow = q0 + w * 16 + col;
  const float* Qr = Q + (size_t)qrow * RS + bh * D;
  short8 qfrag[4];
  #pragma unroll
  for (int ks = 0; ks < 4; ++ks) {
    float4 a0 = *(const float4*)(Qr + ks * 32 + quad * 8);
    float4 a1 = *(const float4*)(Qr + ks * 32 + quad * 8 + 4);
    union { short8 s; unsigned int u[4]; } qf;
    qf.u[0] = pack2bf(a0.x * SCALE_LOG2E, a0.y * SCALE_LOG2E);
    qf.u[1] = pack2bf(a0.z * SCALE_LOG2E, a0.w * SCALE_LOG2E);
    qf.u[2] = pack2bf(a1.x * SCALE_LOG2E, a1.y * SCALE_LOG2E);
    qf.u[3] = pack2bf(a1.z * SCALE_LOG2E, a1.w * SCALE_LOG2E);
    qfrag[ks] = qf.s;
  }

  floatx4 Oacc[8];
  #pragma unroll
  for (int dt = 0; dt < 8; ++dt) {
    #pragma unroll
    for (int e = 0; e < 4; ++e) Oacc[dt][e] = 0.f;
  }
  float lsum[4] = {0.f, 0.f, 0.f, 0.f};

  const int row_g0      = q0 + w * 16 + quad * 4;
  const int jt_maxb     = (q0 + BM - 1) >> 6;
  const int wave_jt_max = (q0 + w * 16 + 15) >> 6;

  for (int jt = 0; jt <= jt_maxb; ++jt) {
    const int j0 = jt * BN;
    __syncthreads();
    if (tid < 256) {
      const int sc = tid & 31;
      const int sg = tid >> 5;
      const float* Vb = V + (size_t)j0 * RS + bh * D;
      float4 vr[8];
      #pragma unroll
      for (int j = 0; j < 8; ++j)
        vr[j] = *(const float4*)(Vb + (sg * 8 + j) * RS + sc * 4);
      #pragma unroll
      for (int i = 0; i < 4; ++i) {
        int d = sc * 4 + i;
        int swz = ((d >> 2) ^ d) & 7;
        union { short8 s; unsigned int u[4]; } wv;
        wv.u[0] = pack2bf(((const float*)&vr[0])[i], ((const float*)&vr[1])[i]);
        wv.u[1] = pack2bf(((const float*)&vr[2])[i], ((const float*)&vr[3])[i]);
        wv.u[2] = pack2bf(((const float*)&vr[4])[i], ((const float*)&vr[5])[i]);
        wv.u[3] = pack2bf(((const float*)&vr[6])[i], ((const float*)&vr[7])[i]);
        *(short8*)&Vt[d * 64 + ((sg ^ swz) * 8)] = wv.s;
      }
    } else {
      const int kt = tid - 256;
      const float* Kb = K + (size_t)j0 * RS + bh * D;
      #pragma unroll
      for (int it = 0; it < 8; ++it) {
        int chunk = kt + it * 256;
        int r = chunk >> 5, c = chunk & 31;
        float4 kv = *(const float4*)(Kb + r * RS + c * 4);
        uint2 u; u.x = pack2bf(kv.x, kv.y); u.y = pack2bf(kv.z, kv.w);
        *(uint2*)&Ks[r * 136 + c * 4] = u;
      }
    }
    __syncthreads();

    if (jt > wave_jt_max) continue;

    floatx4 S[4];
    #pragma unroll
    for (int nt = 0; nt < 4; ++nt) {
      #pragma unroll
      for (int e = 0; e < 4; ++e) S[nt][e] = 0.f;
    }
    #pragma unroll
    for (int ks = 0; ks < 4; ++ks) {
      short8 a = qfrag[ks];
      #pragma unroll
      for (int nt = 0; nt < 4; ++nt) {
        short8 b = *(const short8*)&Ks[(nt * 16 + col) * 136 + ks * 32 + quad * 8];
        S[nt] = __builtin_amdgcn_mfma_f32_16x16x32_bf16(a, b, S[nt], 0, 0, 0);
      }
    }

    const bool diag = (jt == wave_jt_max);
    float p[4][4];
    #pragma unroll
    for (int nt = 0; nt < 4; ++nt) {
      int key = j0 + nt * 16 + col;
      #pragma unroll
      for (int r = 0; r < 4; ++r) {
        float s = S[nt][r];
        if (diag && key > row_g0 + r) s = -INFINITY;
        float pe = __builtin_amdgcn_exp2f(s);
        p[nt][r] = pe;
        lsum[r] += pe;
      }
    }

    #pragma unroll
    for (int nt = 0; nt < 4; ++nt) {
      #pragma unroll
      for (int r = 0; r < 4; ++r) {
        union { float f; unsigned int u; } cv;
        cv.f = p[nt][r];
        unsigned int u = cv.u;
        u += 0x7fffu + ((u >> 16) & 1u);
        Ps[(w * 16 + quad * 4 + r) * VP + nt * 16 + col] = (unsigned short)(u >> 16);
      }
    }

    #pragma unroll
    for (int ks = 0; ks < 2; ++ks) {
      short8 a = *(const short8*)&Ps[(w * 16 + col) * VP + ks * 32 + quad * 8];
      #pragma unroll
      for (int dt = 0; dt < 8; ++dt) {
        int d = dt * 16 + col;
        int swz = ((d >> 2) ^ d) & 7;
        short8 b = *(const short8*)&Vt[d * 64 + (((ks * 4 + quad) ^ swz) * 8)];
        Oacc[dt] = __builtin_amdgcn_mfma_f32_16x16x32_bf16(a, b, Oacc[dt], 0, 0, 0);
      }
    }
  }

  #pragma unroll
  for (int r = 0; r < 4; ++r) {
    float s = lsum[r];
    #pragma unroll
    for (int off = 1; off < 16; off <<= 1)
      s += __shfl_xor(s, off, 64);
    float inv = 1.f / s;
    int row_g = q0 + w * 16 + quad * 4 + r;
    float* Ob = Out + (size_t)row_g * RS + bh * D;
    #pragma unroll
    for (int dt = 0; dt < 8; ++dt)
      Ob[dt * 16 + col] = Oacc[dt][r] * inv;
  }
}

extern "C" void kernel_launch(void* const* d_in, const int* in_sizes, int n_in,
                              void* d_out, int out_size, void* d_ws, size_t ws_size,
                              hipStream_t stream) {
  const float* Q = (const float*)d_in[0];
  const float* K = (const float*)d_in[1];
  const float* V = (const float*)d_in[2];
  float* Out = (float*)d_out;
  const size_t need = (size_t)2 * NBH * SQ * D * sizeof(unsigned short); // 32 MB
  if (ws_size >= need) {
    unsigned short* Kg  = (unsigned short*)d_ws;
    unsigned short* Vtg = Kg + (size_t)NBH * SQ * D;
    prep_kernel<<<dim3(NBH, SQ / BN), dim3(256), 0, stream>>>(K, V, Kg, Vtg);
    fa_fwd_kernel<<<dim3(NBH, SQ / BM), dim3(256), 0, stream>>>(Q, Kg, Vtg, Out);
  } else {
    fa_fwd_kernel_fb<<<dim3(NBH, SQ / BM), dim3(512), 0, stream>>>(Q, K, V, Out);
  }
}

// Round 10
// 203.730 us; speedup vs baseline: 1.6202x; 1.0394x over previous
//
#include <hip/hip_runtime.h>
#include <hip/hip_bf16.h>

typedef __attribute__((ext_vector_type(8))) short short8;
typedef __attribute__((ext_vector_type(4))) float floatx4;
typedef __attribute__((ext_vector_type(4))) _Float16 half4;

constexpr int SQ  = 2048;
constexpr int NBH = 32;     // b*h
constexpr int D   = 128;
constexpr int RS  = 4096;   // fp32 row stride (b*h*d)
constexpr int BM  = 128;    // q rows per block (8 waves x 16 rows)
constexpr int BN  = 64;     // kv rows per tile
constexpr int VP  = 72;     // fallback Ps pitch

// softmax_scale * log2(e): fold into Q so softmax uses exp2 directly
#define SCALE_LOG2E 0.1275310225629712f

__device__ __forceinline__ unsigned int pack2bf(float a, float b) {
  __hip_bfloat162 h = __float22bfloat162_rn(make_float2(a, b));
  union { __hip_bfloat162 h; unsigned int u; } cv; cv.h = h;
  return cv.u;
}

// cvt_pkrtz returns __fp16 ext_vector(2); move it as raw bits.
__device__ __forceinline__ unsigned int pack2h(float a, float b) {
  union { __fp16 __attribute__((ext_vector_type(2))) h; unsigned int u; } cv;
  cv.h = __builtin_amdgcn_cvt_pkrtz(a, b);
  return cv.u;
}

__device__ __forceinline__ void gl_lds16(const unsigned short* g, unsigned short* l) {
  __builtin_amdgcn_global_load_lds(
      (const __attribute__((address_space(1))) unsigned int*)g,
      (__attribute__((address_space(3))) unsigned int*)l, 16, 0, 0);
}

// ===== pre-pass: K -> bf16 [bh][key][d]; V -> f16 V^T [bh][d][key] =====
__global__ __launch_bounds__(256)
void prep_kernel(const float* __restrict__ K, const float* __restrict__ V,
                 unsigned short* __restrict__ Kg, unsigned short* __restrict__ Vtg) {
  __shared__ __align__(16) unsigned short Vl[D * 64];   // 16 KB
  const int bh  = blockIdx.x;
  const int j0  = blockIdx.y * BN;
  const int tid = threadIdx.x;

  const float* Kb = K + (size_t)j0 * RS + bh * D;
  unsigned short* Ko = Kg + ((size_t)bh * SQ + j0) * D;
  #pragma unroll
  for (int it = 0; it < 8; ++it) {
    int chunk = tid + it * 256;
    int r = chunk >> 5, c = chunk & 31;
    float4 kv = *(const float4*)(Kb + r * RS + c * 4);
    uint2 u; u.x = pack2bf(kv.x, kv.y); u.y = pack2bf(kv.z, kv.w);
    *(uint2*)&Ko[r * 128 + c * 4] = u;
  }

  const int sc = tid & 31;   // d-group (float4)
  const int sg = tid >> 5;   // key-chunk (8 keys)
  const float* Vb = V + (size_t)j0 * RS + bh * D;
  float4 vr[8];
  #pragma unroll
  for (int j = 0; j < 8; ++j)
    vr[j] = *(const float4*)(Vb + (sg * 8 + j) * RS + sc * 4);
  #pragma unroll
  for (int i = 0; i < 4; ++i) {
    int d = sc * 4 + i;
    int swz = ((d >> 2) ^ d) & 7;
    union { short8 s; unsigned int u[4]; } w;
    w.u[0] = pack2h(((const float*)&vr[0])[i], ((const float*)&vr[1])[i]);
    w.u[1] = pack2h(((const float*)&vr[2])[i], ((const float*)&vr[3])[i]);
    w.u[2] = pack2h(((const float*)&vr[4])[i], ((const float*)&vr[5])[i]);
    w.u[3] = pack2h(((const float*)&vr[6])[i], ((const float*)&vr[7])[i]);
    *(short8*)&Vl[d * 64 + ((sg ^ swz) * 8)] = w.s;
  }
  __syncthreads();

  unsigned short* Vo = Vtg + (size_t)bh * D * SQ;
  #pragma unroll
  for (int p = 0; p < 4; ++p) {
    int c  = p * 256 + tid;
    int d  = c >> 3, kc = c & 7;
    int swz = ((d >> 2) ^ d) & 7;
    short8 v = *(const short8*)&Vl[d * 64 + ((kc ^ swz) * 8)];
    *(short8*)&Vo[(size_t)d * SQ + j0 + kc * 8] = v;
  }
}

// ===== main: 8 waves x 16 q-rows; S^T layout-chaining, no Ps LDS =====
// QK: S^T = mfma16x16x32_bf16(A=K_frag, B=Q_frag); C-layout key=quad*4+r,
// qrow=col. That IS the B-operand layout of mfma_f32_16x16x16f16
// (B[n=col][k=quad*4+j]), so P^T feeds PV directly from registers.
// PV: O^T += mfma16x16x16f16(A=V^T from LDS (f16 b64 reads), B=P^T).
__global__ __launch_bounds__(512)
void fa_fwd_kernel(const float* __restrict__ Q,
                   const unsigned short* __restrict__ Kg,
                   const unsigned short* __restrict__ Vtg,
                   float* __restrict__ Out) {
  __shared__ __align__(16) unsigned short Ks[BN * 128];   // 16384 B
  __shared__ __align__(16) unsigned short Vt[D * 64];     // 16384 B (f16)
  // total 32768 B

  const int tid  = threadIdx.x;
  const int bh   = blockIdx.x;
  const int qt   = (gridDim.y - 1) - blockIdx.y;  // heavy blocks first
  const int q0   = qt * BM;
  const int w    = tid >> 6;
  const int lane = tid & 63;
  const int quad = lane >> 4;
  const int col  = lane & 15;

  const unsigned short* Kgb  = Kg  + (size_t)bh * SQ * D;
  const unsigned short* Vtgb = Vtg + (size_t)bh * D * SQ;

  // ---- Q fragments (bf16, scaled), wave's 16 rows ----
  const int qrow_g = q0 + w * 16 + col;
  const float* Qr = Q + (size_t)qrow_g * RS + bh * D;
  short8 qfrag[4];
  #pragma unroll
  for (int ks = 0; ks < 4; ++ks) {
    float4 a0 = *(const float4*)(Qr + ks * 32 + quad * 8);
    float4 a1 = *(const float4*)(Qr + ks * 32 + quad * 8 + 4);
    union { short8 s; unsigned int u[4]; } qf;
    qf.u[0] = pack2bf(a0.x * SCALE_LOG2E, a0.y * SCALE_LOG2E);
    qf.u[1] = pack2bf(a0.z * SCALE_LOG2E, a0.w * SCALE_LOG2E);
    qf.u[2] = pack2bf(a1.x * SCALE_LOG2E, a1.y * SCALE_LOG2E);
    qf.u[3] = pack2bf(a1.z * SCALE_LOG2E, a1.w * SCALE_LOG2E);
    qfrag[ks] = qf.s;
  }

  floatx4 Oacc[8];   // O^T tiles: [d=16dt+quad*4+r][qrow=col]
  #pragma unroll
  for (int dt = 0; dt < 8; ++dt)
    #pragma unroll
    for (int e = 0; e < 4; ++e) Oacc[dt][e] = 0.f;
  float lsum = 0.f;  // partial row-sum for qrow=col over this lane's keys

  const int jt_max      = 2 * qt + 1;
  const int wave_jt_max = (q0 + w * 16 + 15) >> 6;

  for (int jt = 0; jt <= jt_max; ++jt) {
    const int j0 = jt * BN;
    __syncthreads();   // prior tile's LDS reads complete

    // ---- staging: 32 x 1KB segments, 4 per wave (8 waves) ----
    #pragma unroll
    for (int t = 0; t < 4; ++t) {
      const int n = w * 4 + t;          // wave-uniform
      if (n < 16) {                      // Ks segment n: keys 4n..4n+3
        const int kl = n * 4 + (lane >> 4);
        const int pc = lane & 15;
        const int lc = pc ^ (kl & 7);
        gl_lds16(Kgb + (size_t)(j0 + kl) * 128 + lc * 8, &Ks[n * 512]);
      } else {                           // Vt segment s: d rows 8s..8s+7
        const int s  = n - 16;
        const int d  = s * 8 + (lane >> 3);
        const int pc = lane & 7;
        const int lc = pc ^ (d & 7);
        gl_lds16(Vtgb + (size_t)d * SQ + j0 + lc * 8, &Vt[s * 512]);
      }
    }
    __syncthreads();   // implicit vmcnt(0): staged data visible

    if (jt > wave_jt_max) continue;   // wave-uniform

    const bool diag = (jt == wave_jt_max);

    // ---- S^T per 16-key tile -> mask -> exp2 -> lsum -> P^T frag ----
    half4 pfrag[4];
    #pragma unroll
    for (int nt = 0; nt < 4; ++nt) {
      floatx4 S;
      #pragma unroll
      for (int e = 0; e < 4; ++e) S[e] = 0.f;
      #pragma unroll
      for (int ks = 0; ks < 4; ++ks) {
        const int r  = nt * 16 + col;
        const int pc = (ks * 4 + quad) ^ (col & 7);
        short8 kf = *(const short8*)&Ks[r * 128 + pc * 8];
        S = __builtin_amdgcn_mfma_f32_16x16x32_bf16(kf, qfrag[ks], S, 0, 0, 0);
      }
      const int keyb = j0 + nt * 16 + quad * 4;
      float pv[4];
      #pragma unroll
      for (int r = 0; r < 4; ++r) {
        float s = S[r];
        if (diag && (keyb + r) > qrow_g) s = -INFINITY;
        pv[r] = __builtin_amdgcn_exp2f(s);
        lsum += pv[r];
      }
      union { half4 h; unsigned int u[2]; } pf;
      pf.u[0] = pack2h(pv[0], pv[1]);
      pf.u[1] = pack2h(pv[2], pv[3]);
      pfrag[nt] = pf.h;
    }

    // ---- O^T += V^T P^T : 4 k-steps x 8 d-tiles, f16 b64 A-frag reads ----
    #pragma unroll
    for (int ntk = 0; ntk < 4; ++ntk) {
      half4 pf = pfrag[ntk];
      #pragma unroll
      for (int dt = 0; dt < 8; ++dt) {
        const int d = dt * 16 + col;
        const int p = (2 * ntk + (quad >> 1)) ^ (d & 7);
        union { half4 h; uint2 u; } vf;
        vf.u = *(const uint2*)&Vt[d * 64 + p * 8 + (quad & 1) * 4];
        Oacc[dt] = __builtin_amdgcn_mfma_f32_16x16x16f16(vf.h, pf, Oacc[dt], 0, 0, 0);
      }
    }
  }

  // ---- epilogue: cross-quad l reduction, normalize, float4 stores ----
  float s = lsum;
  s += __shfl_xor(s, 16, 64);
  s += __shfl_xor(s, 32, 64);
  const float inv = 1.f / s;
  float* Ob = Out + (size_t)qrow_g * RS + bh * D;
  #pragma unroll
  for (int dt = 0; dt < 8; ++dt) {
    float4 o;
    o.x = Oacc[dt][0] * inv;
    o.y = Oacc[dt][1] * inv;
    o.z = Oacc[dt][2] * inv;
    o.w = Oacc[dt][3] * inv;
    *(float4*)&Ob[dt * 16 + quad * 4] = o;
  }
}

// ============ fallback (round-6) if ws_size < 32 MB ============
__global__ __launch_bounds__(512, 2)
void fa_fwd_kernel_fb(const float* __restrict__ Q,
                      const float* __restrict__ K,
                      const float* __restrict__ V,
                      float* __restrict__ Out) {
  __shared__ __align__(16) unsigned short Ks[BN * 136];
  __shared__ __align__(16) unsigned short Vt[D * 64];
  __shared__ __align__(16) unsigned short Ps[8 * 16 * VP];

  const int tid  = threadIdx.x;
  const int bh   = blockIdx.x;
  const int qt   = gridDim.y - 1 - blockIdx.y;
  const int q0   = qt * BM;
  const int w    = tid >> 6;
  const int lane = tid & 63;
  const int quad = lane >> 4;
  const int col  = lane & 15;

  const int qrow = q0 + w * 16 + col;
  const float* Qr = Q + (size_t)qrow * RS + bh * D;
  short8 qfrag[4];
  #pragma unroll
  for (int ks = 0; ks < 4; ++ks) {
    float4 a0 = *(const float4*)(Qr + ks * 32 + quad * 8);
    float4 a1 = *(const float4*)(Qr + ks * 32 + quad * 8 + 4);
    union { short8 s; unsigned int u[4]; } qf;
    qf.u[0] = pack2bf(a0.x * SCALE_LOG2E, a0.y * SCALE_LOG2E);
    qf.u[1] = pack2bf(a0.z * SCALE_LOG2E, a0.w * SCALE_LOG2E);
    qf.u[2] = pack2bf(a1.x * SCALE_LOG2E, a1.y * SCALE_LOG2E);
    qf.u[3] = pack2bf(a1.z * SCALE_LOG2E, a1.w * SCALE_LOG2E);
    qfrag[ks] = qf.s;
  }

  floatx4 Oacc[8];
  #pragma unroll
  for (int dt = 0; dt < 8; ++dt) {
    #pragma unroll
    for (int e = 0; e < 4; ++e) Oacc[dt][e] = 0.f;
  }
  float lsum[4] = {0.f, 0.f, 0.f, 0.f};

  const int row_g0      = q0 + w * 16 + quad * 4;
  const int jt_maxb     = (q0 + BM - 1) >> 6;
  const int wave_jt_max = (q0 + w * 16 + 15) >> 6;

  for (int jt = 0; jt <= jt_maxb; ++jt) {
    const int j0 = jt * BN;
    __syncthreads();
    if (tid < 256) {
      const int sc = tid & 31;
      const int sg = tid >> 5;
      const float* Vb = V + (size_t)j0 * RS + bh * D;
      float4 vr[8];
      #pragma unroll
      for (int j = 0; j < 8; ++j)
        vr[j] = *(const float4*)(Vb + (sg * 8 + j) * RS + sc * 4);
      #pragma unroll
      for (int i = 0; i < 4; ++i) {
        int d = sc * 4 + i;
        int swz = ((d >> 2) ^ d) & 7;
        union { short8 s; unsigned int u[4]; } wv;
        wv.u[0] = pack2bf(((const float*)&vr[0])[i], ((const float*)&vr[1])[i]);
        wv.u[1] = pack2bf(((const float*)&vr[2])[i], ((const float*)&vr[3])[i]);
        wv.u[2] = pack2bf(((const float*)&vr[4])[i], ((const float*)&vr[5])[i]);
        wv.u[3] = pack2bf(((const float*)&vr[6])[i], ((const float*)&vr[7])[i]);
        *(short8*)&Vt[d * 64 + ((sg ^ swz) * 8)] = wv.s;
      }
    } else {
      const int kt = tid - 256;
      const float* Kb = K + (size_t)j0 * RS + bh * D;
      #pragma unroll
      for (int it = 0; it < 8; ++it) {
        int chunk = kt + it * 256;
        int r = chunk >> 5, c = chunk & 31;
        float4 kv = *(const float4*)(Kb + r * RS + c * 4);
        uint2 u; u.x = pack2bf(kv.x, kv.y); u.y = pack2bf(kv.z, kv.w);
        *(uint2*)&Ks[r * 136 + c * 4] = u;
      }
    }
    __syncthreads();

    if (jt > wave_jt_max) continue;

    floatx4 S[4];
    #pragma unroll
    for (int nt = 0; nt < 4; ++nt) {
      #pragma unroll
      for (int e = 0; e < 4; ++e) S[nt][e] = 0.f;
    }
    #pragma unroll
    for (int ks = 0; ks < 4; ++ks) {
      short8 a = qfrag[ks];
      #pragma unroll
      for (int nt = 0; nt < 4; ++nt) {
        short8 b = *(const short8*)&Ks[(nt * 16 + col) * 136 + ks * 32 + quad * 8];
        S[nt] = __builtin_amdgcn_mfma_f32_16x16x32_bf16(a, b, S[nt], 0, 0, 0);
      }
    }

    const bool diag = (jt == wave_jt_max);
    float p[4][4];
    #pragma unroll
    for (int nt = 0; nt < 4; ++nt) {
      int key = j0 + nt * 16 + col;
      #pragma unroll
      for (int r = 0; r < 4; ++r) {
        float s = S[nt][r];
        if (diag && key > row_g0 + r) s = -INFINITY;
        float pe = __builtin_amdgcn_exp2f(s);
        p[nt][r] = pe;
        lsum[r] += pe;
      }
    }

    #pragma unroll
    for (int nt = 0; nt < 4; ++nt) {
      #pragma unroll
      for (int r = 0; r < 4; ++r) {
        union { float f; unsigned int u; } cv;
        cv.f = p[nt][r];
        unsigned int u = cv.u;
        u += 0x7fffu + ((u >> 16) & 1u);
        Ps[(w * 16 + quad * 4 + r) * VP + nt * 16 + col] = (unsigned short)(u >> 16);
      }
    }

    #pragma unroll
    for (int ks = 0; ks < 2; ++ks) {
      short8 a = *(const short8*)&Ps[(w * 16 + col) * VP + ks * 32 + quad * 8];
      #pragma unroll
      for (int dt = 0; dt < 8; ++dt) {
        int d = dt * 16 + col;
        int swz = ((d >> 2) ^ d) & 7;
        short8 b = *(const short8*)&Vt[d * 64 + (((ks * 4 + quad) ^ swz) * 8)];
        Oacc[dt] = __builtin_amdgcn_mfma_f32_16x16x32_bf16(a, b, Oacc[dt], 0, 0, 0);
      }
    }
  }

  #pragma unroll
  for (int r = 0; r < 4; ++r) {
    float s = lsum[r];
    #pragma unroll
    for (int off = 1; off < 16; off <<= 1)
      s += __shfl_xor(s, off, 64);
    float inv = 1.f / s;
    int row_g = q0 + w * 16 + quad * 4 + r;
    float* Ob = Out + (size_t)row_g * RS + bh * D;
    #pragma unroll
    for (int dt = 0; dt < 8; ++dt)
      Ob[dt * 16 + col] = Oacc[dt][r] * inv;
  }
}

extern "C" void kernel_launch(void* const* d_in, const int* in_sizes, int n_in,
                              void* d_out, int out_size, void* d_ws, size_t ws_size,
                              hipStream_t stream) {
  const float* Q = (const float*)d_in[0];
  const float* K = (const float*)d_in[1];
  const float* V = (const float*)d_in[2];
  float* Out = (float*)d_out;
  const size_t need = (size_t)2 * NBH * SQ * D * sizeof(unsigned short); // 32 MB
  if (ws_size >= need) {
    unsigned short* Kg  = (unsigned short*)d_ws;
    unsigned short* Vtg = Kg + (size_t)NBH * SQ * D;
    prep_kernel<<<dim3(NBH, SQ / BN), dim3(256), 0, stream>>>(K, V, Kg, Vtg);
    fa_fwd_kernel<<<dim3(NBH, SQ / BM), dim3(512), 0, stream>>>(Q, Kg, Vtg, Out);
  } else {
    fa_fwd_kernel_fb<<<dim3(NBH, SQ / BM), dim3(512), 0, stream>>>(Q, K, V, Out);
  }
}